// Round 1
// baseline (121.049 us; speedup 1.0000x reference)
//
#include <hip/hip_runtime.h>
#include <hip/hip_bf16.h>
#include <stdint.h>

#define DEVI __device__ __forceinline__

typedef __attribute__((ext_vector_type(8))) short short8;
typedef __attribute__((ext_vector_type(4))) short short4v;
typedef __attribute__((ext_vector_type(16))) float f32x16;
typedef __attribute__((ext_vector_type(4))) float f32x4;

union U8 { short8 s8; unsigned u[4]; };
union U4 { short4v s4; unsigned u[2]; };

DEVI unsigned short f2bf(float f) {
  unsigned u = __builtin_bit_cast(unsigned, f);
  u += 0x7fffu + ((u >> 16) & 1u);
  return (unsigned short)(u >> 16);
}
DEVI unsigned pk2(float lo, float hi) {
  return (unsigned)f2bf(lo) | ((unsigned)f2bf(hi) << 16);
}
DEVI unsigned cvtpk(float lo, float hi) {
  unsigned r;
  asm("v_cvt_pk_bf16_f32 %0, %1, %2" : "=v"(r) : "v"(lo), "v"(hi));
  return r;
}

#define MFMA32 __builtin_amdgcn_mfma_f32_32x32x16_bf16
// p = exp(S/8 - m/8) computed as exp2((S-m)*C), C = 0.125*log2(e)
#define C_L2E 0.18033688011112042f

// ---------------- Path A: attn_i = softmax(img_q^T st_k) * st_v ----------------
// grid 256 = 16 bh * 16 t-blocks; block 512 (8 waves, 32 t per wave)
__global__ __launch_bounds__(512, 2) void attn_img_kernel(
    const float* __restrict__ img, const float* __restrict__ st,
    float* __restrict__ out0) {
  const int tid = threadIdx.x;
  const int bid = blockIdx.x;
  const int bh = bid >> 4;
  const int tb = bid & 15;
  const int b = bh >> 3, h = bh & 7;
  const float* qbase = img + ((size_t)(b * 1536 + h * 64)) * 4096;
  const float* kbase = st + ((size_t)(b * 1536 + 512 + h * 64)) * 1024;
  const float* vbase = st + ((size_t)(b * 1536 + 1024 + h * 64)) * 1024;
  float* obase = out0 + ((size_t)(b * 512 + h * 64)) * 4096;

  __shared__ short Kt[64][72];  // K^T tile: [s][c], 144B rows (16B pad)
  __shared__ short Vl[64][72];  // V tile:   [c][s]

  const int w = tid >> 6;
  const int lane = tid & 63;
  const int hi = lane >> 5;
  const int ln = lane & 31;
  const int tcol = tb * 256 + w * 32 + ln;

  // Hoist Q fragments (B-operand): B[k=c][n=t], k = kstep*16 + hi*8 + j
  short8 qf[4];
#pragma unroll
  for (int k = 0; k < 4; ++k) {
    const float* qp = qbase + (size_t)(k * 16 + hi * 8) * 4096 + tcol;
    float q8[8];
#pragma unroll
    for (int j = 0; j < 8; ++j) q8[j] = qp[(size_t)j * 4096];
    U8 u;
#pragma unroll
    for (int i = 0; i < 4; ++i) u.u[i] = pk2(q8[2 * i], q8[2 * i + 1]);
    qf[k] = u.s8;
  }

  f32x16 oacc0 = {}, oacc1 = {};  // out[c][t]: c-tiles 0-31, 32-63
  float m = -3.0e38f, l = 0.0f;

  const int sl = tid & 63, g = tid >> 6;          // Kt staging coords
  const int vc = tid >> 4, vs4 = (tid & 15) * 4;  // V staging coords

  for (int tile = 0; tile < 16; ++tile) {
    const int s0 = tile * 64;
    if (tile) __syncthreads();
    // stage Kt[s][c] = K[c][s0+s] (bf16)
    {
      const float* kp = kbase + (size_t)(g * 8) * 1024 + s0 + sl;
      float k8[8];
#pragma unroll
      for (int j = 0; j < 8; ++j) k8[j] = kp[(size_t)j * 1024];
      U8 u;
#pragma unroll
      for (int i = 0; i < 4; ++i) u.u[i] = pk2(k8[2 * i], k8[2 * i + 1]);
      *(short8*)&Kt[sl][g * 8] = u.s8;
    }
    // stage Vl[c][s] (bf16)
#pragma unroll
    for (int rep = 0; rep < 2; ++rep) {
      const int cc = vc + 32 * rep;
      f32x4 v4 = *(const f32x4*)(vbase + (size_t)cc * 1024 + s0 + vs4);
      U4 u;
      u.u[0] = pk2(v4[0], v4[1]);
      u.u[1] = pk2(v4[2], v4[3]);
      *(short4v*)&Vl[cc][vs4] = u.s4;
    }
    __syncthreads();

    // scores: D[s][t] = sum_c K[c][s] Q[c][t]  (A = K^T frag, B = Q frag)
    f32x16 sc0 = {}, sc1 = {};
#pragma unroll
    for (int k = 0; k < 4; ++k) {
      short8 a0 = *(const short8*)&Kt[ln][k * 16 + hi * 8];
      sc0 = MFMA32(a0, qf[k], sc0, 0, 0, 0);
    }
#pragma unroll
    for (int k = 0; k < 4; ++k) {
      short8 a1 = *(const short8*)&Kt[32 + ln][k * 16 + hi * 8];
      sc1 = MFMA32(a1, qf[k], sc1, 0, 0, 0);
    }

    // online softmax over the 64 s of this tile (this lane holds 32, partner 32)
    float tmax = sc0[0];
#pragma unroll
    for (int q = 1; q < 16; ++q) tmax = fmaxf(tmax, sc0[q]);
#pragma unroll
    for (int q = 0; q < 16; ++q) tmax = fmaxf(tmax, sc1[q]);
    tmax = fmaxf(tmax, __shfl_xor(tmax, 32));
    const float mnew = fmaxf(m, tmax);
    const float corr = exp2f((m - mnew) * C_L2E);
    m = mnew;
    float psum = 0.f;
#pragma unroll
    for (int q = 0; q < 16; ++q) {
      float p = exp2f((sc0[q] - mnew) * C_L2E);
      sc0[q] = p; psum += p;
    }
#pragma unroll
    for (int q = 0; q < 16; ++q) {
      float p = exp2f((sc1[q] - mnew) * C_L2E);
      sc1[q] = p; psum += p;
    }
    psum += __shfl_xor(psum, 32);
    l = l * corr + psum;
#pragma unroll
    for (int q = 0; q < 16; ++q) { oacc0[q] *= corr; oacc1[q] *= corr; }

    // PV per 32-s subtile: redistribute P (D-layout, 4-s groups) to B-layout (8-s groups)
#pragma unroll
    for (int ss = 0; ss < 2; ++ss) {
      const f32x16& sc = ss ? sc1 : sc0;
      unsigned pb[8], oth[8];
#pragma unroll
      for (int i = 0; i < 8; ++i) pb[i] = cvtpk(sc[2 * i], sc[2 * i + 1]);
#pragma unroll
      for (int i = 0; i < 8; ++i) oth[i] = __shfl_xor(pb[i], 32);
      U8 f0, f1;
      if (hi) {
        f0.u[0] = oth[2]; f0.u[1] = oth[3]; f0.u[2] = pb[2];  f0.u[3] = pb[3];
        f1.u[0] = oth[6]; f1.u[1] = oth[7]; f1.u[2] = pb[6];  f1.u[3] = pb[7];
      } else {
        f0.u[0] = pb[0];  f0.u[1] = pb[1];  f0.u[2] = oth[0]; f0.u[3] = oth[1];
        f1.u[0] = pb[4];  f1.u[1] = pb[5];  f1.u[2] = oth[4]; f1.u[3] = oth[5];
      }
      const int sb = ss * 32 + hi * 8;
#pragma unroll
      for (int k = 0; k < 2; ++k) {
        const short8 bfrag = k ? f1.s8 : f0.s8;
        short8 av0 = *(const short8*)&Vl[ln][sb + k * 16];
        short8 av1 = *(const short8*)&Vl[32 + ln][sb + k * 16];
        oacc0 = MFMA32(av0, bfrag, oacc0, 0, 0, 0);
        oacc1 = MFMA32(av1, bfrag, oacc1, 0, 0, 0);
      }
    }
  }

  const float inv = 1.0f / l;
#pragma unroll
  for (int q = 0; q < 16; ++q) {
    const int c = (q & 3) + 8 * (q >> 2) + 4 * hi;
    obase[(size_t)c * 4096 + tcol] = oacc0[q] * inv;
    obase[(size_t)(c + 32) * 4096 + tcol] = oacc1[q] * inv;
  }
}

// ---- Path B: attn_st = scale^2 * (V_img K_img^T) Q_st  (no softmax -> collapse) ----
// grid 16 (one per bh), block 256 (4 waves)
__global__ __launch_bounds__(256) void attn_st_kernel(
    const float* __restrict__ img, const float* __restrict__ st,
    float* __restrict__ out1) {
  const int tid = threadIdx.x;
  const int bh = blockIdx.x;
  const int b = bh >> 3, h = bh & 7;
  const float* kbase = img + ((size_t)(b * 1536 + 512 + h * 64)) * 4096;
  const float* vbase = img + ((size_t)(b * 1536 + 1024 + h * 64)) * 4096;
  const float* qbase = st + ((size_t)(b * 1536 + h * 64)) * 1024;
  float* o1 = out1 + ((size_t)(b * 512 + h * 64)) * 1024;

  __shared__ float part[4][64][64];  // 64 KB: per-wave M partials, then reused for Ms

  const int w = tid >> 6, lane = tid & 63, hi = lane >> 5, ln = lane & 31;

  // phase 1: per-wave M partial over its 1024-s chunk; M[c][c'] = sum_s V[c][s] K[c'][s]
  f32x16 m00 = {}, m01 = {}, m10 = {}, m11 = {};
  for (int s0 = w * 1024; s0 < w * 1024 + 1024; s0 += 16) {
    const int sa = s0 + hi * 8;
    short8 av[2], bk[2];
#pragma unroll
    for (int ci = 0; ci < 2; ++ci) {
      const float* vp = vbase + (size_t)(ci * 32 + ln) * 4096 + sa;
      f32x4 lo = *(const f32x4*)vp, hp = *(const f32x4*)(vp + 4);
      U8 u;
      u.u[0] = pk2(lo[0], lo[1]); u.u[1] = pk2(lo[2], lo[3]);
      u.u[2] = pk2(hp[0], hp[1]); u.u[3] = pk2(hp[2], hp[3]);
      av[ci] = u.s8;
    }
#pragma unroll
    for (int cj = 0; cj < 2; ++cj) {
      const float* kp = kbase + (size_t)(cj * 32 + ln) * 4096 + sa;
      f32x4 lo = *(const f32x4*)kp, hp = *(const f32x4*)(kp + 4);
      U8 u;
      u.u[0] = pk2(lo[0], lo[1]); u.u[1] = pk2(lo[2], lo[3]);
      u.u[2] = pk2(hp[0], hp[1]); u.u[3] = pk2(hp[2], hp[3]);
      bk[cj] = u.s8;
    }
    m00 = MFMA32(av[0], bk[0], m00, 0, 0, 0);
    m01 = MFMA32(av[0], bk[1], m01, 0, 0, 0);
    m10 = MFMA32(av[1], bk[0], m10, 0, 0, 0);
    m11 = MFMA32(av[1], bk[1], m11, 0, 0, 0);
  }
#pragma unroll
  for (int q = 0; q < 16; ++q) {
    const int cr = (q & 3) + 8 * (q >> 2) + 4 * hi;
    part[w][cr][ln] = m00[q];
    part[w][cr][32 + ln] = m01[q];
    part[w][32 + cr][ln] = m10[q];
    part[w][32 + cr][32 + ln] = m11[q];
  }
  __syncthreads();

  // reduce 4 partials -> Ms (scale^2 applied), stored XOR-swizzled into part[0] area
  float sum[16];
#pragma unroll
  for (int i = 0; i < 16; ++i) {
    const int e = tid + i * 256;
    const int c = e >> 6, cp = e & 63;
    sum[i] = (part[0][c][cp] + part[1][c][cp] + part[2][c][cp] + part[3][c][cp]) * 0.125f;
  }
  __syncthreads();
  char* msb = (char*)&part[0][0][0];
#pragma unroll
  for (int i = 0; i < 16; ++i) {
    const int e = tid + i * 256;
    const int c = e >> 6, cp = e & 63;
    *(float*)(msb + c * 256 + ((cp * 4) ^ ((c & 7) << 5))) = sum[i];
  }
  __syncthreads();

  // phase 2: out1[c][t] = sum_c' Ms[c][c'] * q[c'][t]  (A = Ms, B = Q_st)
  short8 aM0[4], aM1[4];
#pragma unroll
  for (int k = 0; k < 4; ++k) {
#pragma unroll
    for (int ci = 0; ci < 2; ++ci) {
      const int row = ci * 32 + ln;
      const int bo = k * 64 + hi * 32;
      const char* rp = msb + row * 256;
      const int swz = (row & 7) << 5;
      f32x4 lo = *(const f32x4*)(rp + (bo ^ swz));
      f32x4 hp = *(const f32x4*)(rp + ((bo + 16) ^ swz));
      U8 u;
      u.u[0] = pk2(lo[0], lo[1]); u.u[1] = pk2(lo[2], lo[3]);
      u.u[2] = pk2(hp[0], hp[1]); u.u[3] = pk2(hp[2], hp[3]);
      if (ci) aM1[k] = u.s8; else aM0[k] = u.s8;
    }
  }
  for (int nt = 0; nt < 8; ++nt) {
    const int t = w * 256 + nt * 32 + ln;
    short8 bq[4];
#pragma unroll
    for (int k = 0; k < 4; ++k) {
      const float* qp = qbase + (size_t)(k * 16 + hi * 8) * 1024 + t;
      float q8[8];
#pragma unroll
      for (int j = 0; j < 8; ++j) q8[j] = qp[(size_t)j * 1024];
      U8 u;
#pragma unroll
      for (int i = 0; i < 4; ++i) u.u[i] = pk2(q8[2 * i], q8[2 * i + 1]);
      bq[k] = u.s8;
    }
    f32x16 a0 = {}, a1 = {};
#pragma unroll
    for (int k = 0; k < 4; ++k) {
      a0 = MFMA32(aM0[k], bq[k], a0, 0, 0, 0);
      a1 = MFMA32(aM1[k], bq[k], a1, 0, 0, 0);
    }
#pragma unroll
    for (int q = 0; q < 16; ++q) {
      const int cr = (q & 3) + 8 * (q >> 2) + 4 * hi;
      o1[(size_t)cr * 1024 + t] = a0[q];
      o1[(size_t)(cr + 32) * 1024 + t] = a1[q];
    }
  }
}

extern "C" void kernel_launch(void* const* d_in, const int* in_sizes, int n_in,
                              void* d_out, int out_size, void* d_ws, size_t ws_size,
                              hipStream_t stream) {
  const float* img = (const float*)d_in[0];
  const float* st = (const float*)d_in[1];
  float* out0 = (float*)d_out;
  float* out1 = out0 + (size_t)2 * 512 * 4096;
  hipLaunchKernelGGL(attn_img_kernel, dim3(256), dim3(512), 0, stream, img, st, out0);
  hipLaunchKernelGGL(attn_st_kernel, dim3(16), dim3(256), 0, stream, img, st, out1);
}

// Round 2
// 73.385 us; speedup vs baseline: 1.6495x; 1.6495x over previous
//
#include <hip/hip_runtime.h>
#include <hip/hip_bf16.h>
#include <stdint.h>

#define DEVI __device__ __forceinline__

typedef __attribute__((ext_vector_type(8))) short short8;
typedef __attribute__((ext_vector_type(4))) short short4v;
typedef __attribute__((ext_vector_type(16))) float f32x16;
typedef __attribute__((ext_vector_type(4))) float f32x4;

union U8 { short8 s8; unsigned u[4]; };
union U4 { short4v s4; unsigned u[2]; };

DEVI unsigned short f2bf(float f) {
  unsigned u = __builtin_bit_cast(unsigned, f);
  u += 0x7fffu + ((u >> 16) & 1u);
  return (unsigned short)(u >> 16);
}
DEVI unsigned pk2(float lo, float hi) {
  return (unsigned)f2bf(lo) | ((unsigned)f2bf(hi) << 16);
}
DEVI unsigned cvtpk(float lo, float hi) {
  unsigned r;
  asm("v_cvt_pk_bf16_f32 %0, %1, %2" : "=v"(r) : "v"(lo), "v"(hi));
  return r;
}

#define MFMA32 __builtin_amdgcn_mfma_f32_32x32x16_bf16
// p = exp(S/8 - m/8) computed as exp2((S-m)*C), C = 0.125*log2(e)
#define C_L2E 0.18033688011112042f

// ---------------- Path A: attn_i = softmax(img_q^T st_k) * st_v ----------------
// grid 256 = 16 bh * 16 t-blocks; block 512 (8 waves, 32 t per wave)
__global__ __launch_bounds__(512, 2) void attn_img_kernel(
    const float* __restrict__ img, const float* __restrict__ st,
    float* __restrict__ out0) {
  const int tid = threadIdx.x;
  const int bid = blockIdx.x;
  const int bh = bid >> 4;
  const int tb = bid & 15;
  const int b = bh >> 3, h = bh & 7;
  const float* qbase = img + ((size_t)(b * 1536 + h * 64)) * 4096;
  const float* kbase = st + ((size_t)(b * 1536 + 512 + h * 64)) * 1024;
  const float* vbase = st + ((size_t)(b * 1536 + 1024 + h * 64)) * 1024;
  float* obase = out0 + ((size_t)(b * 512 + h * 64)) * 4096;

  __shared__ short Kt[64][72];  // K^T tile: [s][c], 144B rows (16B pad)
  __shared__ short Vl[64][72];  // V tile:   [c][s]

  const int w = tid >> 6;
  const int lane = tid & 63;
  const int hi = lane >> 5;
  const int ln = lane & 31;
  const int tcol = tb * 256 + w * 32 + ln;

  // Hoist Q fragments (B-operand): B[k=c][n=t], k = kstep*16 + hi*8 + j
  short8 qf[4];
#pragma unroll
  for (int k = 0; k < 4; ++k) {
    const float* qp = qbase + (size_t)(k * 16 + hi * 8) * 4096 + tcol;
    float q8[8];
#pragma unroll
    for (int j = 0; j < 8; ++j) q8[j] = qp[(size_t)j * 4096];
    U8 u;
#pragma unroll
    for (int i = 0; i < 4; ++i) u.u[i] = pk2(q8[2 * i], q8[2 * i + 1]);
    qf[k] = u.s8;
  }

  f32x16 oacc0 = {}, oacc1 = {};  // out[c][t]: c-tiles 0-31, 32-63
  float m = -3.0e38f, l = 0.0f;

  const int sl = tid & 63, g = tid >> 6;          // Kt staging coords
  const int vc = tid >> 4, vs4 = (tid & 15) * 4;  // V staging coords

  for (int tile = 0; tile < 16; ++tile) {
    const int s0 = tile * 64;
    if (tile) __syncthreads();
    // stage Kt[s][c] = K[c][s0+s] (bf16)
    {
      const float* kp = kbase + (size_t)(g * 8) * 1024 + s0 + sl;
      float k8[8];
#pragma unroll
      for (int j = 0; j < 8; ++j) k8[j] = kp[(size_t)j * 1024];
      U8 u;
#pragma unroll
      for (int i = 0; i < 4; ++i) u.u[i] = pk2(k8[2 * i], k8[2 * i + 1]);
      *(short8*)&Kt[sl][g * 8] = u.s8;
    }
    // stage Vl[c][s] (bf16)
#pragma unroll
    for (int rep = 0; rep < 2; ++rep) {
      const int cc = vc + 32 * rep;
      f32x4 v4 = *(const f32x4*)(vbase + (size_t)cc * 1024 + s0 + vs4);
      U4 u;
      u.u[0] = pk2(v4[0], v4[1]);
      u.u[1] = pk2(v4[2], v4[3]);
      *(short4v*)&Vl[cc][vs4] = u.s4;
    }
    __syncthreads();

    // scores: D[s][t] = sum_c K[c][s] Q[c][t]  (A = K^T frag, B = Q frag)
    f32x16 sc0 = {}, sc1 = {};
#pragma unroll
    for (int k = 0; k < 4; ++k) {
      short8 a0 = *(const short8*)&Kt[ln][k * 16 + hi * 8];
      sc0 = MFMA32(a0, qf[k], sc0, 0, 0, 0);
    }
#pragma unroll
    for (int k = 0; k < 4; ++k) {
      short8 a1 = *(const short8*)&Kt[32 + ln][k * 16 + hi * 8];
      sc1 = MFMA32(a1, qf[k], sc1, 0, 0, 0);
    }

    // online softmax over the 64 s of this tile (this lane holds 32, partner 32)
    float tmax = sc0[0];
#pragma unroll
    for (int q = 1; q < 16; ++q) tmax = fmaxf(tmax, sc0[q]);
#pragma unroll
    for (int q = 0; q < 16; ++q) tmax = fmaxf(tmax, sc1[q]);
    tmax = fmaxf(tmax, __shfl_xor(tmax, 32));
    const float mnew = fmaxf(m, tmax);
    const float corr = exp2f((m - mnew) * C_L2E);
    m = mnew;
    float psum = 0.f;
#pragma unroll
    for (int q = 0; q < 16; ++q) {
      float p = exp2f((sc0[q] - mnew) * C_L2E);
      sc0[q] = p; psum += p;
    }
#pragma unroll
    for (int q = 0; q < 16; ++q) {
      float p = exp2f((sc1[q] - mnew) * C_L2E);
      sc1[q] = p; psum += p;
    }
    psum += __shfl_xor(psum, 32);
    l = l * corr + psum;
#pragma unroll
    for (int q = 0; q < 16; ++q) { oacc0[q] *= corr; oacc1[q] *= corr; }

    // PV per 32-s subtile: redistribute P (D-layout, 4-s groups) to B-layout (8-s groups)
#pragma unroll
    for (int ss = 0; ss < 2; ++ss) {
      const f32x16& sc = ss ? sc1 : sc0;
      unsigned pb[8], oth[8];
#pragma unroll
      for (int i = 0; i < 8; ++i) pb[i] = cvtpk(sc[2 * i], sc[2 * i + 1]);
#pragma unroll
      for (int i = 0; i < 8; ++i) oth[i] = __shfl_xor(pb[i], 32);
      U8 f0, f1;
      if (hi) {
        f0.u[0] = oth[2]; f0.u[1] = oth[3]; f0.u[2] = pb[2];  f0.u[3] = pb[3];
        f1.u[0] = oth[6]; f1.u[1] = oth[7]; f1.u[2] = pb[6];  f1.u[3] = pb[7];
      } else {
        f0.u[0] = pb[0];  f0.u[1] = pb[1];  f0.u[2] = oth[0]; f0.u[3] = oth[1];
        f1.u[0] = pb[4];  f1.u[1] = pb[5];  f1.u[2] = oth[4]; f1.u[3] = oth[5];
      }
      const int sb = ss * 32 + hi * 8;
#pragma unroll
      for (int k = 0; k < 2; ++k) {
        const short8 bfrag = k ? f1.s8 : f0.s8;
        short8 av0 = *(const short8*)&Vl[ln][sb + k * 16];
        short8 av1 = *(const short8*)&Vl[32 + ln][sb + k * 16];
        oacc0 = MFMA32(av0, bfrag, oacc0, 0, 0, 0);
        oacc1 = MFMA32(av1, bfrag, oacc1, 0, 0, 0);
      }
    }
  }

  const float inv = 1.0f / l;
#pragma unroll
  for (int q = 0; q < 16; ++q) {
    const int c = (q & 3) + 8 * (q >> 2) + 4 * hi;
    obase[(size_t)c * 4096 + tcol] = oacc0[q] * inv;
    obase[(size_t)(c + 32) * 4096 + tcol] = oacc1[q] * inv;
  }
}

// ---- Path B: attn_st = scale^2 * (V_img K_img^T) Q_st  (no softmax -> collapse) ----
// Split 1: Gram partials. grid 256 = 16 bh * 16 s-chunks (256 s each); block 256.
// PART=true: write per-chunk partials to ws[bh][chunk][4096] (4 MB).
// PART=false: atomicAdd into ws[bh][4096] (256 KB, pre-zeroed via memsetAsync).
template <bool PART>
__global__ __launch_bounds__(256) void gram_kernel(
    const float* __restrict__ img, float* __restrict__ Mws) {
  const int tid = threadIdx.x;
  const int bid = blockIdx.x;
  const int bh = bid >> 4;
  const int chunk = bid & 15;
  const int b = bh >> 3, h = bh & 7;
  const float* kbase = img + ((size_t)(b * 1536 + 512 + h * 64)) * 4096;
  const float* vbase = img + ((size_t)(b * 1536 + 1024 + h * 64)) * 4096;

  const int w = tid >> 6, lane = tid & 63, hi = lane >> 5, ln = lane & 31;

  // M[c][c'] = sum_s V[c][s] K[c'][s]; this wave covers 64 s
  f32x16 m00 = {}, m01 = {}, m10 = {}, m11 = {};
  const int sbeg = chunk * 256 + w * 64;
  for (int s0 = sbeg; s0 < sbeg + 64; s0 += 16) {
    const int sa = s0 + hi * 8;
    short8 av[2], bk[2];
#pragma unroll
    for (int ci = 0; ci < 2; ++ci) {
      const float* vp = vbase + (size_t)(ci * 32 + ln) * 4096 + sa;
      f32x4 lo = *(const f32x4*)vp, hp = *(const f32x4*)(vp + 4);
      U8 u;
      u.u[0] = pk2(lo[0], lo[1]); u.u[1] = pk2(lo[2], lo[3]);
      u.u[2] = pk2(hp[0], hp[1]); u.u[3] = pk2(hp[2], hp[3]);
      av[ci] = u.s8;
    }
#pragma unroll
    for (int cj = 0; cj < 2; ++cj) {
      const float* kp = kbase + (size_t)(cj * 32 + ln) * 4096 + sa;
      f32x4 lo = *(const f32x4*)kp, hp = *(const f32x4*)(kp + 4);
      U8 u;
      u.u[0] = pk2(lo[0], lo[1]); u.u[1] = pk2(lo[2], lo[3]);
      u.u[2] = pk2(hp[0], hp[1]); u.u[3] = pk2(hp[2], hp[3]);
      bk[cj] = u.s8;
    }
    m00 = MFMA32(av[0], bk[0], m00, 0, 0, 0);
    m01 = MFMA32(av[0], bk[1], m01, 0, 0, 0);
    m10 = MFMA32(av[1], bk[0], m10, 0, 0, 0);
    m11 = MFMA32(av[1], bk[1], m11, 0, 0, 0);
  }

  __shared__ float part[4][64][64];  // 64 KB
#pragma unroll
  for (int q = 0; q < 16; ++q) {
    const int cr = (q & 3) + 8 * (q >> 2) + 4 * hi;
    part[w][cr][ln] = m00[q];
    part[w][cr][32 + ln] = m01[q];
    part[w][32 + cr][ln] = m10[q];
    part[w][32 + cr][32 + ln] = m11[q];
  }
  __syncthreads();

#pragma unroll
  for (int i = 0; i < 16; ++i) {
    const int e = tid + i * 256;
    const int c = e >> 6, cp = e & 63;
    const float s =
        (part[0][c][cp] + part[1][c][cp] + part[2][c][cp] + part[3][c][cp]) * 0.125f;
    if (PART)
      Mws[(size_t)bid * 4096 + c * 64 + cp] = s;
    else
      atomicAdd(&Mws[(size_t)bh * 4096 + c * 64 + cp], s);
  }
}

// Split 2: out1[c][t] = sum_c' Ms[c][c'] * q_st[c'][t].
// grid 64 = 16 bh * 4 t-tiles (256 t each); block 256 (4 waves, 64 t per wave).
template <bool PART>
__global__ __launch_bounds__(256) void attn_st2_kernel(
    const float* __restrict__ st, const float* __restrict__ Mws,
    float* __restrict__ out1) {
  const int tid = threadIdx.x;
  const int bh = blockIdx.x >> 2;
  const int tt = blockIdx.x & 3;
  const int b = bh >> 3, h = bh & 7;
  const float* qbase = st + ((size_t)(b * 1536 + h * 64)) * 1024;
  float* o1 = out1 + ((size_t)(b * 512 + h * 64)) * 1024;

  __shared__ float Ms[64][64];  // XOR-swizzled rows (row stride 256B)
  char* msb = (char*)&Ms[0][0];

#pragma unroll
  for (int i = 0; i < 16; ++i) {
    const int e = tid + i * 256;
    const int c = e >> 6, cp = e & 63;
    float s;
    if (PART) {
      const float* mp = Mws + (size_t)bh * 16 * 4096 + c * 64 + cp;
      s = 0.f;
#pragma unroll
      for (int ch = 0; ch < 16; ++ch) s += mp[(size_t)ch * 4096];
    } else {
      s = Mws[(size_t)bh * 4096 + c * 64 + cp];
    }
    *(float*)(msb + c * 256 + ((cp * 4) ^ ((c & 7) << 5))) = s;
  }
  __syncthreads();

  const int w = tid >> 6, lane = tid & 63, hi = lane >> 5, ln = lane & 31;

  short8 aM0[4], aM1[4];
#pragma unroll
  for (int k = 0; k < 4; ++k) {
#pragma unroll
    for (int ci = 0; ci < 2; ++ci) {
      const int row = ci * 32 + ln;
      const int bo = k * 64 + hi * 32;
      const char* rp = msb + row * 256;
      const int swz = (row & 7) << 5;
      f32x4 lo = *(const f32x4*)(rp + (bo ^ swz));
      f32x4 hp = *(const f32x4*)(rp + ((bo + 16) ^ swz));
      U8 u;
      u.u[0] = pk2(lo[0], lo[1]); u.u[1] = pk2(lo[2], lo[3]);
      u.u[2] = pk2(hp[0], hp[1]); u.u[3] = pk2(hp[2], hp[3]);
      if (ci) aM1[k] = u.s8; else aM0[k] = u.s8;
    }
  }

#pragma unroll
  for (int nt = 0; nt < 2; ++nt) {
    const int t = tt * 256 + w * 64 + nt * 32 + ln;
    short8 bq[4];
#pragma unroll
    for (int k = 0; k < 4; ++k) {
      const float* qp = qbase + (size_t)(k * 16 + hi * 8) * 1024 + t;
      float q8[8];
#pragma unroll
      for (int j = 0; j < 8; ++j) q8[j] = qp[(size_t)j * 1024];
      U8 u;
#pragma unroll
      for (int i = 0; i < 4; ++i) u.u[i] = pk2(q8[2 * i], q8[2 * i + 1]);
      bq[k] = u.s8;
    }
    f32x16 a0 = {}, a1 = {};
#pragma unroll
    for (int k = 0; k < 4; ++k) {
      a0 = MFMA32(aM0[k], bq[k], a0, 0, 0, 0);
      a1 = MFMA32(aM1[k], bq[k], a1, 0, 0, 0);
    }
#pragma unroll
    for (int q = 0; q < 16; ++q) {
      const int cr = (q & 3) + 8 * (q >> 2) + 4 * hi;
      o1[(size_t)cr * 1024 + t] = a0[q];
      o1[(size_t)(cr + 32) * 1024 + t] = a1[q];
    }
  }
}

extern "C" void kernel_launch(void* const* d_in, const int* in_sizes, int n_in,
                              void* d_out, int out_size, void* d_ws, size_t ws_size,
                              hipStream_t stream) {
  const float* img = (const float*)d_in[0];
  const float* st = (const float*)d_in[1];
  float* out0 = (float*)d_out;
  float* out1 = out0 + (size_t)2 * 512 * 4096;
  float* Mws = (float*)d_ws;

  hipLaunchKernelGGL(attn_img_kernel, dim3(256), dim3(512), 0, stream, img, st, out0);

  const bool part = ws_size >= (size_t)16 * 16 * 4096 * 4;
  if (part) {
    hipLaunchKernelGGL((gram_kernel<true>), dim3(256), dim3(256), 0, stream, img, Mws);
    hipLaunchKernelGGL((attn_st2_kernel<true>), dim3(64), dim3(256), 0, stream, st, Mws, out1);
  } else {
    hipMemsetAsync(d_ws, 0, (size_t)16 * 4096 * 4, stream);
    hipLaunchKernelGGL((gram_kernel<false>), dim3(256), dim3(256), 0, stream, img, Mws);
    hipLaunchKernelGGL((attn_st2_kernel<false>), dim3(64), dim3(256), 0, stream, st, Mws, out1);
  }
}